// Round 3
// baseline (264.968 us; speedup 1.0000x reference)
//
#include <hip/hip_runtime.h>

// CRF NLL, round 3: exp-space forward recursion, one wave per batch.
// Changes vs r2 (theory: exposed HBM latency from conditional prefetch):
//  - unconditional feats load with CLAMPED ADDRESS (select moved off the
//    loaded data -> no vmcnt(0) inside the step)
//  - prefetch ring depth 3 (~3 steps of latency cover as the step shrinks)
//  - ldexpf replaced by exact 2^-k bit-trick scale on the scalar path
#define BB 512
#define SS 512
#define TT 64
#define START_TAG 62
#define STOP_TAG 63

#define LOG2E 1.4426950408889634f
#define LN2   0.6931471805599453f

__device__ __forceinline__ float bcast0(float x) {
    return __int_as_float(__builtin_amdgcn_readfirstlane(__float_as_int(x)));
}
__device__ __forceinline__ float rlane(float x, int l) {
    return __int_as_float(__builtin_amdgcn_readlane(__float_as_int(x), l));
}

__global__ __launch_bounds__(128) void crf_main(
    const float* __restrict__ feats, const int* __restrict__ mask,
    const int* __restrict__ tags, const float* __restrict__ trans,
    float* __restrict__ out)
{
    const int b    = blockIdx.x;
    const int tid  = threadIdx.x;
    const int lane = tid & 63;

    const float* frow = feats + (size_t)b * SS * TT;
    const int*   mrow = mask + b * SS;

    if (tid < 64) {
        // ---------------- forward (log partition), one wave per batch --------
        int cnt = 0;
        #pragma unroll
        for (int s = lane; s < SS; s += 64) cnt += (mrow[s] != 0);
        #pragma unroll
        for (int off = 32; off; off >>= 1) cnt += __shfl_xor(cnt, off);
        const int len = cnt;                       // >= SS/2 >= 256

        // M[from=i][to=lane] in exp2 space (constant across the scan)
        float vt[64];
        #pragma unroll
        for (int i = 0; i < 64; ++i)
            vt[i] = __builtin_amdgcn_exp2f(trans[i * TT + lane] * LOG2E);

        // init: P0[to] = f[0,to] + trans[START,to];  E = exp2((P0-offs)*log2e)
        const float P0   = frow[lane] + trans[START_TAG * TT + lane];
        const float offs = bcast0(P0);
        float E = __builtin_amdgcn_exp2f((P0 - offs) * LOG2E);
        int ksum = 0;

        // prefetch ring, depth 3: f0 -> row s, f1 -> row s+1, f2 -> row s+2
        float f0 = frow[1 * TT + lane];
        float f1 = frow[2 * TT + lane];
        float f2 = frow[3 * TT + lane];

        for (int s = 1; s < len; ++s) {
            const float f_use = f0;
            f0 = f1;
            f1 = f2;
            // unconditional load, clamped uniform address (never waits on data
            // inside this step; consumed 3 iterations later)
            const int sp = (s + 4 < SS) ? (s + 4) : (SS - 1);
            f2 = frow[(size_t)sp * TT + lane];

            // fe only depends on f_use (loaded 3 steps ago) -> issues early
            const float fe = __builtin_amdgcn_exp2f(f_use * LOG2E);

            float a0 = 0.f, a1 = 0.f, a2 = 0.f, a3 = 0.f;
            #pragma unroll
            for (int i = 0; i < 64; i += 4) {
                const float e0 = rlane(E, i + 0);
                const float e1 = rlane(E, i + 1);
                const float e2 = rlane(E, i + 2);
                const float e3 = rlane(E, i + 3);
                a0 = fmaf(e0, vt[i + 0], a0);
                a1 = fmaf(e1, vt[i + 1], a1);
                a2 = fmaf(e2, vt[i + 2], a2);
                a3 = fmaf(e3, vt[i + 3], a3);
            }
            const float D = (a0 + a1) + (a2 + a3);

            // exact power-of-2 rebase via exponent bits of D at lane 0
            // (D > 0 and normal: exp bits in [1,254])
            const int ebits = (__builtin_amdgcn_readfirstlane(__float_as_int(D))
                               >> 23) & 0xff;
            ksum += ebits - 127;
            const float scale = __int_as_float((254 - ebits) << 23); // 2^-(e-127)
            E = (fe * D) * scale;
        }

        // final transition to STOP: lse_from(P[from] + trans[from,STOP])
        const float ts = __builtin_amdgcn_exp2f(trans[lane * TT + STOP_TAG] * LOG2E);
        float e = E * ts;
        #pragma unroll
        for (int off = 32; off; off >>= 1) e += __shfl_xor(e, off);

        if (lane == 0)
            atomicAdd(out, offs + (float)ksum * LN2
                           + LN2 * __builtin_amdgcn_logf(e));
    } else {
        // ---------------- gold score, wave 1 of the block --------------------
        const int* trow = tags + b * SS;
        int   cnt = 0;
        float acc = 0.f;
        for (int s = lane; s < SS; s += 64) {
            if (mrow[s] != 0) {
                ++cnt;
                const int tag  = trow[s];
                const int prev = (s == 0) ? START_TAG : trow[s - 1];
                acc += frow[(size_t)s * TT + tag] + trans[prev * TT + tag];
            }
        }
        #pragma unroll
        for (int off = 32; off; off >>= 1) {
            acc += __shfl_xor(acc, off);
            cnt += __shfl_xor(cnt, off);
        }
        if (lane == 0) {
            const int end_id = trow[cnt - 1];
            atomicAdd(out, -(acc + trans[end_id * TT + STOP_TAG]));
        }
    }
}

__global__ void zero_out(float* out) { out[0] = 0.f; }

extern "C" void kernel_launch(void* const* d_in, const int* in_sizes, int n_in,
                              void* d_out, int out_size, void* d_ws, size_t ws_size,
                              hipStream_t stream) {
    const float* feats = (const float*)d_in[0];   // (B,S,T) f32
    const int*   mask  = (const int*)d_in[1];     // (B,S)   int (0/1)
    const int*   tags  = (const int*)d_in[2];     // (B,S)   int
    const float* trans = (const float*)d_in[3];   // (T,T)   f32
    float* out = (float*)d_out;

    zero_out<<<1, 1, 0, stream>>>(out);
    crf_main<<<BB, 128, 0, stream>>>(feats, mask, tags, trans, out);
}

// Round 4
// 206.009 us; speedup vs baseline: 1.2862x; 1.2862x over previous
//
#include <hip/hip_runtime.h>

// CRF NLL, round 4: exp-space forward recursion, one wave per batch.
// Changes vs r3 (theory: two serializations — readlane->fmac SGPR hazard and
// vmcnt(0) exposed by ring-rotation v_movs):
//  - readlane broadcasts software-pipelined in groups of 8 (>=8 instrs
//    between each v_readlane and its v_fmac consumer)
//  - scan unrolled x4 with an 8-deep feats ring in a fully-unrolled array
//    (register-renamed; rows consumed 8 steps after issue)
//  - exact pow2 rescale only every 4th step (range-safe: growth < 2^15/step)
#define BB 512
#define SS 512
#define TT 64
#define START_TAG 62
#define STOP_TAG 63

#define LOG2E 1.4426950408889634f
#define LN2   0.6931471805599453f

__device__ __forceinline__ float bcast0(float x) {
    return __int_as_float(__builtin_amdgcn_readfirstlane(__float_as_int(x)));
}
__device__ __forceinline__ float rlane(float x, int l) {
    return __int_as_float(__builtin_amdgcn_readlane(__float_as_int(x), l));
}

// one matvec in exp space: D[to] = sum_from E[from] * vt[from][to]
// readlanes pipelined one group of 8 ahead of their consumers.
__device__ __forceinline__ float matvec64(const float E, const float* vt) {
    float a0 = 0.f, a1 = 0.f, a2 = 0.f, a3 = 0.f;
    float t[8], u[8];
    #pragma unroll
    for (int j = 0; j < 8; ++j) t[j] = rlane(E, j);
    #pragma unroll
    for (int g = 0; g < 8; ++g) {
        if (g < 7) {
            #pragma unroll
            for (int j = 0; j < 8; ++j) u[j] = rlane(E, 8 * g + 8 + j);
        }
        a0 = fmaf(t[0], vt[8 * g + 0], a0);
        a1 = fmaf(t[1], vt[8 * g + 1], a1);
        a2 = fmaf(t[2], vt[8 * g + 2], a2);
        a3 = fmaf(t[3], vt[8 * g + 3], a3);
        a0 = fmaf(t[4], vt[8 * g + 4], a0);
        a1 = fmaf(t[5], vt[8 * g + 5], a1);
        a2 = fmaf(t[6], vt[8 * g + 6], a2);
        a3 = fmaf(t[7], vt[8 * g + 7], a3);
        #pragma unroll
        for (int j = 0; j < 8; ++j) t[j] = u[j];
    }
    return (a0 + a1) + (a2 + a3);
}

__global__ __launch_bounds__(128) void crf_main(
    const float* __restrict__ feats, const int* __restrict__ mask,
    const int* __restrict__ tags, const float* __restrict__ trans,
    float* __restrict__ out)
{
    const int b    = blockIdx.x;
    const int tid  = threadIdx.x;
    const int lane = tid & 63;

    const float* frow = feats + (size_t)b * SS * TT;
    const int*   mrow = mask + b * SS;

    if (tid < 64) {
        // ---------------- forward (log partition), one wave per batch --------
        int cnt = 0;
        #pragma unroll
        for (int s = lane; s < SS; s += 64) cnt += (mrow[s] != 0);
        #pragma unroll
        for (int off = 32; off; off >>= 1) cnt += __shfl_xor(cnt, off);
        const int len = cnt;                       // in [SS/2, SS]

        // M[from=i][to=lane] in exp2 space (constant across the scan)
        float vt[64];
        #pragma unroll
        for (int i = 0; i < 64; ++i)
            vt[i] = __builtin_amdgcn_exp2f(trans[i * TT + lane] * LOG2E);

        // init: P0[to] = f[0,to] + trans[START,to];  E = exp2((P0-offs)*log2e)
        const float P0   = frow[lane] + trans[START_TAG * TT + lane];
        const float offs = bcast0(P0);
        float E = __builtin_amdgcn_exp2f((P0 - offs) * LOG2E);
        int ksum = 0;

        // 8-deep feats row ring (1 VGPR per row), rows s .. s+7 for s=1
        float fr[8];
        #pragma unroll
        for (int j = 0; j < 8; ++j) {
            int r = 1 + j; if (r > SS - 1) r = SS - 1;
            fr[j] = frow[(size_t)r * TT + lane];
        }

        int s = 1;
        for (; s + 3 < len; s += 4) {
            // issue next block's loads (rows s+8..s+11); waited only at the
            // ring shift at block bottom (~4 steps of latency cover), and
            // consumed 8 steps after issue.
            float n0, n1, n2, n3;
            {
                int r0 = s + 8,  r1 = s + 9,  r2 = s + 10, r3 = s + 11;
                if (r0 > SS - 1) r0 = SS - 1;
                if (r1 > SS - 1) r1 = SS - 1;
                if (r2 > SS - 1) r2 = SS - 1;
                if (r3 > SS - 1) r3 = SS - 1;
                n0 = frow[(size_t)r0 * TT + lane];
                n1 = frow[(size_t)r1 * TT + lane];
                n2 = frow[(size_t)r2 * TT + lane];
                n3 = frow[(size_t)r3 * TT + lane];
            }

            // 3 plain steps (no rescale; growth bounded < 2^15/step)
            #pragma unroll
            for (int j = 0; j < 3; ++j) {
                const float fe = __builtin_amdgcn_exp2f(fr[j] * LOG2E);
                const float D  = matvec64(E, vt);
                E = fe * D;
            }
            // 4th step with exact pow2 rescale
            {
                const float fe = __builtin_amdgcn_exp2f(fr[3] * LOG2E);
                const float D  = matvec64(E, vt);
                const int ebits = (__builtin_amdgcn_readfirstlane(
                                       __float_as_int(D)) >> 23) & 0xff;
                ksum += ebits - 127;
                const float scale = __int_as_float((254 - ebits) << 23);
                E = fe * (D * scale);
            }

            // ring shift (fully unrolled -> register renaming, movs for the
            // new loads land after the block's compute)
            #pragma unroll
            for (int j = 0; j < 4; ++j) fr[j] = fr[j + 4];
            fr[4] = n0; fr[5] = n1; fr[6] = n2; fr[7] = n3;
        }
        // tail (<= 3 steps), rows already in the ring
        for (int j = 0; s < len; ++s, ++j) {
            const float fe = __builtin_amdgcn_exp2f(fr[j] * LOG2E);
            const float D  = matvec64(E, vt);
            const int ebits = (__builtin_amdgcn_readfirstlane(
                                   __float_as_int(D)) >> 23) & 0xff;
            ksum += ebits - 127;
            const float scale = __int_as_float((254 - ebits) << 23);
            E = fe * (D * scale);
        }

        // final transition to STOP: lse_from(P[from] + trans[from,STOP])
        const float ts = __builtin_amdgcn_exp2f(trans[lane * TT + STOP_TAG] * LOG2E);
        float e = E * ts;
        #pragma unroll
        for (int off = 32; off; off >>= 1) e += __shfl_xor(e, off);

        if (lane == 0)
            atomicAdd(out, offs + (float)ksum * LN2
                           + LN2 * __builtin_amdgcn_logf(e));
    } else {
        // ---------------- gold score, wave 1 of the block --------------------
        const int* trow = tags + b * SS;
        int   cnt = 0;
        float acc = 0.f;
        for (int s = lane; s < SS; s += 64) {
            if (mrow[s] != 0) {
                ++cnt;
                const int tag  = trow[s];
                const int prev = (s == 0) ? START_TAG : trow[s - 1];
                acc += frow[(size_t)s * TT + tag] + trans[prev * TT + tag];
            }
        }
        #pragma unroll
        for (int off = 32; off; off >>= 1) {
            acc += __shfl_xor(acc, off);
            cnt += __shfl_xor(cnt, off);
        }
        if (lane == 0) {
            const int end_id = trow[cnt - 1];
            atomicAdd(out, -(acc + trans[end_id * TT + STOP_TAG]));
        }
    }
}

__global__ void zero_out(float* out) { out[0] = 0.f; }

extern "C" void kernel_launch(void* const* d_in, const int* in_sizes, int n_in,
                              void* d_out, int out_size, void* d_ws, size_t ws_size,
                              hipStream_t stream) {
    const float* feats = (const float*)d_in[0];   // (B,S,T) f32
    const int*   mask  = (const int*)d_in[1];     // (B,S)   int (0/1)
    const int*   tags  = (const int*)d_in[2];     // (B,S)   int
    const float* trans = (const float*)d_in[3];   // (T,T)   f32
    float* out = (float*)d_out;

    zero_out<<<1, 1, 0, stream>>>(out);
    crf_main<<<BB, 128, 0, stream>>>(feats, mask, tags, trans, out);
}